// Round 2
// baseline (708.869 us; speedup 1.0000x reference)
//
#include <hip/hip_runtime.h>
#include <stdint.h>

typedef __bf16 bf16;
typedef __bf16 v8bf __attribute__((ext_vector_type(8)));
typedef __bf16 v4bf __attribute__((ext_vector_type(4)));
typedef float f32x4 __attribute__((ext_vector_type(4)));

#define MFMA16x16x32(a, b, c) __builtin_amdgcn_mfma_f32_16x16x32_bf16((a), (b), (c), 0, 0, 0)

__device__ __forceinline__ void async_ld16(const float* g, float* l) {
  __builtin_amdgcn_global_load_lds(
      (const __attribute__((address_space(1))) uint32_t*)g,
      (__attribute__((address_space(3))) uint32_t*)l, 16, 0, 0);
}

// ---------------- prep kernels ----------------
// Wt physical K layout is permuted so that within each 16-channel chunk,
// k-slot sub-half 0 holds channels {0-3,8-11} and sub-half 1 holds
// {4-7,12-15}: channel pairs seen by q-groups then differ by 4*204 words
// = 16 banks -> stencil LDS reads become 2-way (free) instead of 4-way.
__global__ __launch_bounds__(64) void prep_wt(const float* __restrict__ wfuse,
                                              const float* __restrict__ whpw,
                                              const float* __restrict__ wvpw,
                                              bf16* __restrict__ Wt) {
  int id = blockIdx.x * 64 + threadIdx.x;  // 32768 total
  int o = id >> 8, k = id & 255;
  int k7 = k & 127, kk = k7 >> 4, sl = k7 & 15, sub = sl >> 3, e = sl & 7;
  int ki = kk * 16 + (e + (e & 4)) + sub * 4;  // permuted semantic channel
  const float* fr = wfuse + o * 256 + (k < 128 ? 0 : 128);
  const float* pw = (k < 128) ? whpw : wvpw;
  float a0 = 0.f, a1 = 0.f, a2 = 0.f, a3 = 0.f;
#pragma unroll 8
  for (int j = 0; j < 128; j += 4) {
    a0 = fmaf(fr[j + 0], pw[(j + 0) * 128 + ki], a0);
    a1 = fmaf(fr[j + 1], pw[(j + 1) * 128 + ki], a1);
    a2 = fmaf(fr[j + 2], pw[(j + 2) * 128 + ki], a2);
    a3 = fmaf(fr[j + 3], pw[(j + 3) * 128 + ki], a3);
  }
  Wt[o * 256 + k] = (bf16)((a0 + a1) + (a2 + a3));
}

__global__ void prep_dm(const float* __restrict__ wdm1,
                        const float* __restrict__ wdm2,
                        bf16* __restrict__ W1, bf16* __restrict__ W2) {
  int id = blockIdx.x * 256 + threadIdx.x;  // 8192
  if (id < 4096) W1[id] = (bf16)wdm1[id];
  else           W2[id - 4096] = (bf16)wdm2[id - 4096];
}

// ---------------- fused main kernel ----------------
// 1024 blocks = (b:2)x(hi:64)x(wchunk:8); tile 5 rows x 40 cols = 200 pos.
// LDS 38432 B, VGPR pinned <=64 -> 4 blocks/CU (32 waves) and the
// 1024-block grid is exactly one 4/CU round (no straggler tail).
// N-tiles of 16: 13 valid (tile 12 half); wave w owns tiles {w, w+8<=12}.
__global__ __launch_bounds__(512, 8) void fused_main(
    const float* __restrict__ x,
    const float* __restrict__ whdw,   // [128][5]
    const float* __restrict__ wvdw,   // [128][5]
    const bf16* __restrict__ Wt,      // [128][256] (K permuted, see prep_wt)
    const bf16* __restrict__ W1,      // [32][128]
    const bf16* __restrict__ W2,      // [128][32]
    const float* __restrict__ scalep,
    float* __restrict__ out) {
  __shared__ __align__(16) char smemc[38432];
  float* xs0 = (float*)smemc;                    // [16][204] fp32 (13056 B)
  float* xs1 = (float*)(smemc + 13056);          // [16][204]
  float* whs = (float*)(smemc + 26112);          // [128][12] (48B rows)
  float* wvs = (float*)(smemc + 32288);          // [128][12], +32B bank stagger

  const int tid = threadIdx.x;
  const int w = tid >> 6, lane = tid & 63, ln16 = lane & 15, q = lane >> 4;
  const int hv = q >> 1;          // 0: horizontal stencil, 1: vertical
  const int csel = (q & 1) * 4;   // channel-set select within 16-ch chunk
  const bool has1 = (w <= 4);     // s=1 tile (w+8) valid only if <=12

  const int bx = blockIdx.x;
  const int wc = bx & 7, hi = (bx >> 3) & 63, b = bx >> 9;
  const size_t xbase = (size_t)b * 13107200 + (size_t)(hi * 5) * 320 + (size_t)(wc * 40);
  const float* gx = x + xbase;

  // stage dw weights (rows padded to 12 floats: dch=4 -> 16-bank offset)
  for (int i = tid; i < 1280; i += 512) {
    int j = (i < 640) ? i : (i - 640);
    int c = j / 5, t = j - c * 5;
    float v = (i < 640) ? whdw[j] : wvdw[j];
    ((i < 640) ? whs : wvs)[c * 12 + t] = v;
  }
  // zero the per-plane pad slots (floats 200..203) of both x buffers
  if (tid < 128) {
    float* bufp = (tid & 64) ? xs1 : xs0;
    int c = (tid & 63) >> 2, p = tid & 3;
    bufp[c * 204 + 200 + p] = 0.f;
  }

  // packed per-s position info: a | col<<8 | aw<<16
  int pk[2];
#pragma unroll
  for (int s = 0; s < 2; ++s) {
    int pos = (w + 8 * s) * 16 + ln16;
    if (pos > 199) pos = 199;
    int a = pos / 40;
    int col = pos - a * 40;
    int aw = col - (col / 5) * 5;
    pk[s] = a | (col << 8) | (aw << 16);
  }

  // async stage of one 16-channel x chunk: wave w loads channels w and w+8;
  // 50 16B-slots per channel (lanes 0..49), LDS base wave-uniform.
  auto stage = [&](int kk, float* buf) {
    const int c0k = kk * 16;
#pragma unroll
    for (int h2 = 0; h2 < 2; ++h2) {
      const int c = w + 8 * h2;
      const float* gc = gx + (size_t)(c0k + c) * 102400;
      float* lb = buf + c * 204;
      if (lane < 50) {
        int r = lane / 10, c4 = lane - r * 10;
        async_ld16(gc + r * 320 + c4 * 4, lb);
      }
    }
  };

  f32x4 acc[2][8];
#pragma unroll
  for (int s = 0; s < 2; ++s)
#pragma unroll
    for (int m = 0; m < 8; ++m) acc[s][m] = (f32x4){0.f, 0.f, 0.f, 0.f};

  stage(0, xs0);

  for (int kk = 0; kk < 8; ++kk) {
    float* cur = (kk & 1) ? xs1 : xs0;
    float* nxt = (kk & 1) ? xs0 : xs1;
    const int c0 = kk * 16;
    __syncthreads();  // drains cur's DMA; closes readers of nxt's old data

    if (kk < 7) stage(kk + 1, nxt);

    // stencil + lrelu -> B fragments (zero-pad slot handles masking)
    const float* wbase = (hv ? wvs : whs) + c0 * 12;
    v8bf bvs[2];
#pragma unroll
    for (int s = 0; s < 2; ++s) {
      if (s == 1 && !has1) break;
      const int a = pk[s] & 255, col = (pk[s] >> 8) & 255, aw = pk[s] >> 16;
      const int base = a * 40 + col;
      int tap[5];
#pragma unroll
      for (int t = 0; t < 5; ++t) {
        const int d = t - 2;
        const int th = ((unsigned)(aw + d) < 5u) ? (base + d) : 200;
        const int tv = ((unsigned)(a + d) < 5u) ? (base + d * 40) : 200;
        tap[t] = hv ? tv : th;
      }
#pragma unroll 4
      for (int c = 0; c < 8; ++c) {
        const int ch = c + (c & 4) + csel;  // {0-3,8-11} or {4-7,12-15}
        const float4 wv4 = *(const float4*)(wbase + ch * 12);
        const float w4v = wbase[ch * 12 + 4];
        const float* xp = cur + ch * 204;
        float d = wv4.x * xp[tap[0]];
        d = fmaf(wv4.y, xp[tap[1]], d);
        d = fmaf(wv4.z, xp[tap[2]], d);
        d = fmaf(wv4.w, xp[tap[3]], d);
        d = fmaf(w4v, xp[tap[4]], d);
        d = fmaxf(d, 0.f) + 0.1f * fminf(d, 0.f);
        bvs[s][c] = (bf16)d;
      }
    }

    // A fragments after stencil (short liveness; latency overlaps across waves)
    v8bf af[8];
    const int koff = c0 + (q & 1) * 8 + hv * 128;
#pragma unroll
    for (int m = 0; m < 8; ++m)
      af[m] = *(const v8bf*)(Wt + (m * 16 + ln16) * 256 + koff);
#pragma unroll
    for (int m = 0; m < 8; ++m)
      acc[0][m] = MFMA16x16x32(af[m], bvs[0], acc[0][m]);
    if (has1) {
#pragma unroll
      for (int m = 0; m < 8; ++m)
        acc[1][m] = MFMA16x16x32(af[m], bvs[1], acc[1][m]);
    }
  }
  __syncthreads();  // all xs/weight readers done; overlay epilogue buffers

  // per-wave private epilogue buffers (no cross-wave traffic, no barriers).
  // ts overlays es: per-wave strictly sequential write->read->overwrite.
  bf16* es = (bf16*)(smemc + w * 4608);            // [16 pos][144], XOR-swz
  bf16* ts = es;                                    // [16 pos][40]
  const float scl = scalep[0];
  // XOR swizzle in 8-bf16 (16B) granules; col < 128 so no row overflow
#define ESI(row, colv) ((row) * 144 + ((colv) ^ (((row) & 7) << 3)))

#pragma unroll
  for (int s = 0; s < 2; ++s) {
    const int nt = w + 8 * s;
    if (nt <= 12) {
      // 1) epi C-frags -> es[pos][o] bf16
#pragma unroll
      for (int m = 0; m < 8; ++m) {
        v4bf v;
        v[0] = (bf16)acc[s][m][0];
        v[1] = (bf16)acc[s][m][1];
        v[2] = (bf16)acc[s][m][2];
        v[3] = (bf16)acc[s][m][3];
        *(v4bf*)(es + ESI(ln16, m * 16 + q * 4)) = v;
      }
      // 2) t = lrelu(Wdm1 @ epi): M=32 (2 tiles), K=128 (4 steps)
      f32x4 tacc[2];
      tacc[0] = (f32x4){0.f, 0.f, 0.f, 0.f};
      tacc[1] = (f32x4){0.f, 0.f, 0.f, 0.f};
#pragma unroll
      for (int ks = 0; ks < 4; ++ks) {
        v8bf bfr = *(const v8bf*)(es + ESI(ln16, ks * 32 + q * 8));
#pragma unroll
        for (int m2 = 0; m2 < 2; ++m2) {
          v8bf afr = *(const v8bf*)(W1 + (m2 * 16 + ln16) * 128 + ks * 32 + q * 8);
          tacc[m2] = MFMA16x16x32(afr, bfr, tacc[m2]);
        }
      }
      // 3) lrelu(t) -> ts[pos][d] bf16 (es no longer needed; safe overlay)
#pragma unroll
      for (int m2 = 0; m2 < 2; ++m2) {
        v4bf v;
#pragma unroll
        for (int r = 0; r < 4; ++r) {
          float tv = tacc[m2][r];
          tv = fmaxf(tv, 0.f) + 0.1f * fminf(tv, 0.f);
          v[r] = (bf16)tv;
        }
        *(v4bf*)(ts + ln16 * 40 + m2 * 16 + q * 4) = v;
      }
      // 4) dw = Wdm2 @ t; 5) out = x + scale*epi*sigmoid(dw)
      v8bf tb = *(const v8bf*)(ts + ln16 * 40 + q * 8);
      const int pos = nt * 16 + ln16;
      const bool valid = (pos < 200);
      const int a = pos / 40;
      const int col = pos - a * 40;
      const size_t gb = xbase + (size_t)(a * 320 + col);
#pragma unroll
      for (int m = 0; m < 8; ++m) {
        v8bf afr2 = *(const v8bf*)(W2 + (m * 16 + ln16) * 32 + q * 8);
        f32x4 z = {0.f, 0.f, 0.f, 0.f};
        f32x4 dacc = MFMA16x16x32(afr2, tb, z);
        if (valid) {
#pragma unroll
          for (int r = 0; r < 4; ++r) {
            const int o = m * 16 + q * 4 + r;
            const float sig = 1.0f / (1.0f + __expf(-dacc[r]));
            const size_t g = gb + (size_t)o * 102400;
            out[g] = x[g] + scl * acc[s][m][r] * sig;
          }
        }
      }
    }
  }
#undef ESI
}

// ---------------- launcher ----------------
extern "C" void kernel_launch(void* const* d_in, const int* in_sizes, int n_in,
                              void* d_out, int out_size, void* d_ws, size_t ws_size,
                              hipStream_t stream) {
  (void)in_sizes; (void)n_in; (void)out_size; (void)ws_size;
  const float* x     = (const float*)d_in[0];
  const float* whdw  = (const float*)d_in[1];
  const float* whpw  = (const float*)d_in[2];
  const float* wvdw  = (const float*)d_in[3];
  const float* wvpw  = (const float*)d_in[4];
  const float* wdm1  = (const float*)d_in[5];
  const float* wdm2  = (const float*)d_in[6];
  const float* wfuse = (const float*)d_in[7];
  const float* scale = (const float*)d_in[8];

  bf16* Wt = (bf16*)d_ws;          // 128*256 bf16
  bf16* W1 = Wt + 32768;           // 32*128
  bf16* W2 = W1 + 4096;            // 128*32

  prep_wt<<<512, 64, 0, stream>>>(wfuse, whpw, wvpw, Wt);
  prep_dm<<<32, 256, 0, stream>>>(wdm1, wdm2, W1, W2);
  fused_main<<<1024, 512, 0, stream>>>(x, whdw, wvdw, Wt, W1, W2, scale, (float*)d_out);
}

// Round 3
// 336.216 us; speedup vs baseline: 2.1084x; 2.1084x over previous
//
#include <hip/hip_runtime.h>
#include <stdint.h>

typedef __bf16 bf16;
typedef __bf16 v8bf __attribute__((ext_vector_type(8)));
typedef __bf16 v4bf __attribute__((ext_vector_type(4)));
typedef float f32x4 __attribute__((ext_vector_type(4)));

#define MFMA16x16x32(a, b, c) __builtin_amdgcn_mfma_f32_16x16x32_bf16((a), (b), (c), 0, 0, 0)

__device__ __forceinline__ void async_ld16(const float* g, float* l) {
  __builtin_amdgcn_global_load_lds(
      (const __attribute__((address_space(1))) uint32_t*)g,
      (__attribute__((address_space(3))) uint32_t*)l, 16, 0, 0);
}

// ---------------- prep kernels ----------------
// Wt physical K layout is permuted so that within each 16-channel chunk,
// k-slot sub-half 0 holds channels {0-3,8-11} and sub-half 1 holds
// {4-7,12-15}: channel pairs seen by q-groups then differ by 4*204 words
// = 16 banks -> stencil LDS reads become 2-way (free) instead of 4-way.
__global__ __launch_bounds__(64) void prep_wt(const float* __restrict__ wfuse,
                                              const float* __restrict__ whpw,
                                              const float* __restrict__ wvpw,
                                              bf16* __restrict__ Wt) {
  int id = blockIdx.x * 64 + threadIdx.x;  // 32768 total
  int o = id >> 8, k = id & 255;
  int k7 = k & 127, kk = k7 >> 4, sl = k7 & 15, sub = sl >> 3, e = sl & 7;
  int ki = kk * 16 + (e + (e & 4)) + sub * 4;  // permuted semantic channel
  const float* fr = wfuse + o * 256 + (k < 128 ? 0 : 128);
  const float* pw = (k < 128) ? whpw : wvpw;
  float a0 = 0.f, a1 = 0.f, a2 = 0.f, a3 = 0.f;
#pragma unroll 8
  for (int j = 0; j < 128; j += 4) {
    a0 = fmaf(fr[j + 0], pw[(j + 0) * 128 + ki], a0);
    a1 = fmaf(fr[j + 1], pw[(j + 1) * 128 + ki], a1);
    a2 = fmaf(fr[j + 2], pw[(j + 2) * 128 + ki], a2);
    a3 = fmaf(fr[j + 3], pw[(j + 3) * 128 + ki], a3);
  }
  Wt[o * 256 + k] = (bf16)((a0 + a1) + (a2 + a3));
}

__global__ void prep_dm(const float* __restrict__ wdm1,
                        const float* __restrict__ wdm2,
                        bf16* __restrict__ W1, bf16* __restrict__ W2) {
  int id = blockIdx.x * 256 + threadIdx.x;  // 8192
  if (id < 4096) W1[id] = (bf16)wdm1[id];
  else           W2[id - 4096] = (bf16)wdm2[id - 4096];
}

// ---------------- fused main kernel ----------------
// 1024 blocks = (b:2)x(hi:64)x(wchunk:8); tile 5 rows x 40 cols = 200 pos.
// launch_bounds (512,4): 128 unified regs/wave budget. Kernel needs ~64
// arch VGPR + ~50 AGPR acc -> 4 waves/SIMD (2 blocks/CU) is the reg-limited
// ceiling; do NOT request 8 waves/EU (that forces 64-reg budget -> acc
// spills to scratch, 1.8 GB of scratch traffic, 3x slowdown — measured r1).
// N-tiles of 16: 13 valid (tile 12 half); wave w owns tiles {w, w+8<=12}.
__global__ __launch_bounds__(512, 4) void fused_main(
    const float* __restrict__ x,
    const float* __restrict__ whdw,   // [128][5]
    const float* __restrict__ wvdw,   // [128][5]
    const bf16* __restrict__ Wt,      // [128][256] (K permuted, see prep_wt)
    const bf16* __restrict__ W1,      // [32][128]
    const bf16* __restrict__ W2,      // [128][32]
    const float* __restrict__ scalep,
    float* __restrict__ out) {
  __shared__ __align__(16) char smemc[38432];
  float* xs0 = (float*)smemc;                    // [16][204] fp32 (13056 B)
  float* xs1 = (float*)(smemc + 13056);          // [16][204]
  float* whs = (float*)(smemc + 26112);          // [128][12] (48B rows)
  float* wvs = (float*)(smemc + 32288);          // [128][12], +32B bank stagger

  const int tid = threadIdx.x;
  const int w = tid >> 6, lane = tid & 63, ln16 = lane & 15, q = lane >> 4;
  const int hv = q >> 1;          // 0: horizontal stencil, 1: vertical
  const int csel = (q & 1) * 4;   // channel-set select within 16-ch chunk
  const bool has1 = (w <= 4);     // s=1 tile (w+8) valid only if <=12

  const int bx = blockIdx.x;
  const int wc = bx & 7, hi = (bx >> 3) & 63, b = bx >> 9;
  const size_t xbase = (size_t)b * 13107200 + (size_t)(hi * 5) * 320 + (size_t)(wc * 40);
  const float* gx = x + xbase;

  // stage dw weights (rows padded to 12 floats: dch=4 -> 16-bank offset)
  for (int i = tid; i < 1280; i += 512) {
    int j = (i < 640) ? i : (i - 640);
    int c = j / 5, t = j - c * 5;
    float v = (i < 640) ? whdw[j] : wvdw[j];
    ((i < 640) ? whs : wvs)[c * 12 + t] = v;
  }
  // zero the per-plane pad slots (floats 200..203) of both x buffers
  if (tid < 128) {
    float* bufp = (tid & 64) ? xs1 : xs0;
    int c = (tid & 63) >> 2, p = tid & 3;
    bufp[c * 204 + 200 + p] = 0.f;
  }

  // packed per-s position info: a | col<<8 | aw<<16
  int pk[2];
#pragma unroll
  for (int s = 0; s < 2; ++s) {
    int pos = (w + 8 * s) * 16 + ln16;
    if (pos > 199) pos = 199;
    int a = pos / 40;
    int col = pos - a * 40;
    int aw = col - (col / 5) * 5;
    pk[s] = a | (col << 8) | (aw << 16);
  }

  // async stage of one 16-channel x chunk: wave w loads channels w and w+8;
  // 50 16B-slots per channel (lanes 0..49), LDS base wave-uniform.
  auto stage = [&](int kk, float* buf) {
    const int c0k = kk * 16;
#pragma unroll
    for (int h2 = 0; h2 < 2; ++h2) {
      const int c = w + 8 * h2;
      const float* gc = gx + (size_t)(c0k + c) * 102400;
      float* lb = buf + c * 204;
      if (lane < 50) {
        int r = lane / 10, c4 = lane - r * 10;
        async_ld16(gc + r * 320 + c4 * 4, lb);
      }
    }
  };

  f32x4 acc[2][8];
#pragma unroll
  for (int s = 0; s < 2; ++s)
#pragma unroll
    for (int m = 0; m < 8; ++m) acc[s][m] = (f32x4){0.f, 0.f, 0.f, 0.f};

  stage(0, xs0);

  for (int kk = 0; kk < 8; ++kk) {
    float* cur = (kk & 1) ? xs1 : xs0;
    float* nxt = (kk & 1) ? xs0 : xs1;
    const int c0 = kk * 16;
    __syncthreads();  // drains cur's DMA; closes readers of nxt's old data

    if (kk < 7) stage(kk + 1, nxt);

    // stencil + lrelu -> B fragments (zero-pad slot handles masking)
    const float* wbase = (hv ? wvs : whs) + c0 * 12;
    v8bf bvs[2];
#pragma unroll
    for (int s = 0; s < 2; ++s) {
      if (s == 1 && !has1) break;
      const int a = pk[s] & 255, col = (pk[s] >> 8) & 255, aw = pk[s] >> 16;
      const int base = a * 40 + col;
      int tap[5];
#pragma unroll
      for (int t = 0; t < 5; ++t) {
        const int d = t - 2;
        const int th = ((unsigned)(aw + d) < 5u) ? (base + d) : 200;
        const int tv = ((unsigned)(a + d) < 5u) ? (base + d * 40) : 200;
        tap[t] = hv ? tv : th;
      }
#pragma unroll 4
      for (int c = 0; c < 8; ++c) {
        const int ch = c + (c & 4) + csel;  // {0-3,8-11} or {4-7,12-15}
        const float4 wv4 = *(const float4*)(wbase + ch * 12);
        const float w4v = wbase[ch * 12 + 4];
        const float* xp = cur + ch * 204;
        float d = wv4.x * xp[tap[0]];
        d = fmaf(wv4.y, xp[tap[1]], d);
        d = fmaf(wv4.z, xp[tap[2]], d);
        d = fmaf(wv4.w, xp[tap[3]], d);
        d = fmaf(w4v, xp[tap[4]], d);
        d = fmaxf(d, 0.f) + 0.1f * fminf(d, 0.f);
        bvs[s][c] = (bf16)d;
      }
    }

    // A fragments after stencil (short liveness; latency overlaps across waves)
    v8bf af[8];
    const int koff = c0 + (q & 1) * 8 + hv * 128;
#pragma unroll
    for (int m = 0; m < 8; ++m)
      af[m] = *(const v8bf*)(Wt + (m * 16 + ln16) * 256 + koff);
#pragma unroll
    for (int m = 0; m < 8; ++m)
      acc[0][m] = MFMA16x16x32(af[m], bvs[0], acc[0][m]);
    if (has1) {
#pragma unroll
      for (int m = 0; m < 8; ++m)
        acc[1][m] = MFMA16x16x32(af[m], bvs[1], acc[1][m]);
    }
  }
  __syncthreads();  // all xs/weight readers done; overlay epilogue buffers

  // per-wave private epilogue buffers (no cross-wave traffic, no barriers).
  // ts overlays es: per-wave strictly sequential write->read->overwrite.
  bf16* es = (bf16*)(smemc + w * 4608);            // [16 pos][144], XOR-swz
  bf16* ts = es;                                    // [16 pos][40]
  const float scl = scalep[0];
  // XOR swizzle in 8-bf16 (16B) granules; col < 128 so no row overflow
#define ESI(row, colv) ((row) * 144 + ((colv) ^ (((row) & 7) << 3)))

#pragma unroll
  for (int s = 0; s < 2; ++s) {
    const int nt = w + 8 * s;
    if (nt <= 12) {
      // 1) epi C-frags -> es[pos][o] bf16
#pragma unroll
      for (int m = 0; m < 8; ++m) {
        v4bf v;
        v[0] = (bf16)acc[s][m][0];
        v[1] = (bf16)acc[s][m][1];
        v[2] = (bf16)acc[s][m][2];
        v[3] = (bf16)acc[s][m][3];
        *(v4bf*)(es + ESI(ln16, m * 16 + q * 4)) = v;
      }
      // 2) t = lrelu(Wdm1 @ epi): M=32 (2 tiles), K=128 (4 steps)
      f32x4 tacc[2];
      tacc[0] = (f32x4){0.f, 0.f, 0.f, 0.f};
      tacc[1] = (f32x4){0.f, 0.f, 0.f, 0.f};
#pragma unroll
      for (int ks = 0; ks < 4; ++ks) {
        v8bf bfr = *(const v8bf*)(es + ESI(ln16, ks * 32 + q * 8));
#pragma unroll
        for (int m2 = 0; m2 < 2; ++m2) {
          v8bf afr = *(const v8bf*)(W1 + (m2 * 16 + ln16) * 128 + ks * 32 + q * 8);
          tacc[m2] = MFMA16x16x32(afr, bfr, tacc[m2]);
        }
      }
      // 3) lrelu(t) -> ts[pos][d] bf16 (es no longer needed; safe overlay)
#pragma unroll
      for (int m2 = 0; m2 < 2; ++m2) {
        v4bf v;
#pragma unroll
        for (int r = 0; r < 4; ++r) {
          float tv = tacc[m2][r];
          tv = fmaxf(tv, 0.f) + 0.1f * fminf(tv, 0.f);
          v[r] = (bf16)tv;
        }
        *(v4bf*)(ts + ln16 * 40 + m2 * 16 + q * 4) = v;
      }
      // 4) dw = Wdm2 @ t; 5) out = x + scale*epi*sigmoid(dw)
      v8bf tb = *(const v8bf*)(ts + ln16 * 40 + q * 8);
      const int pos = nt * 16 + ln16;
      const bool valid = (pos < 200);
      const int a = pos / 40;
      const int col = pos - a * 40;
      const size_t gb = xbase + (size_t)(a * 320 + col);
#pragma unroll
      for (int m = 0; m < 8; ++m) {
        v8bf afr2 = *(const v8bf*)(W2 + (m * 16 + ln16) * 32 + q * 8);
        f32x4 z = {0.f, 0.f, 0.f, 0.f};
        f32x4 dacc = MFMA16x16x32(afr2, tb, z);
        if (valid) {
#pragma unroll
          for (int r = 0; r < 4; ++r) {
            const int o = m * 16 + q * 4 + r;
            const float sig = 1.0f / (1.0f + __expf(-dacc[r]));
            const size_t g = gb + (size_t)o * 102400;
            out[g] = x[g] + scl * acc[s][m][r] * sig;
          }
        }
      }
    }
  }
#undef ESI
}

// ---------------- launcher ----------------
extern "C" void kernel_launch(void* const* d_in, const int* in_sizes, int n_in,
                              void* d_out, int out_size, void* d_ws, size_t ws_size,
                              hipStream_t stream) {
  (void)in_sizes; (void)n_in; (void)out_size; (void)ws_size;
  const float* x     = (const float*)d_in[0];
  const float* whdw  = (const float*)d_in[1];
  const float* whpw  = (const float*)d_in[2];
  const float* wvdw  = (const float*)d_in[3];
  const float* wvpw  = (const float*)d_in[4];
  const float* wdm1  = (const float*)d_in[5];
  const float* wdm2  = (const float*)d_in[6];
  const float* wfuse = (const float*)d_in[7];
  const float* scale = (const float*)d_in[8];

  bf16* Wt = (bf16*)d_ws;          // 128*256 bf16
  bf16* W1 = Wt + 32768;           // 32*128
  bf16* W2 = W1 + 4096;            // 128*32

  prep_wt<<<512, 64, 0, stream>>>(wfuse, whpw, wvpw, Wt);
  prep_dm<<<32, 256, 0, stream>>>(wdm1, wdm2, W1, W2);
  fused_main<<<1024, 512, 0, stream>>>(x, whdw, wvdw, Wt, W1, W2, scale, (float*)d_out);
}